// Round 13
// baseline (3696.978 us; speedup 1.0000x reference)
//
#include <hip/hip_runtime.h>

typedef unsigned short u16;
typedef signed char s8;
typedef __attribute__((ext_vector_type(4))) float f32x4;
typedef __attribute__((ext_vector_type(4))) int i32x4;

#define M_ROWS 8192
#define N_OUT  14336
#define K_IN   4096
#define NTILE  64   // K_IN / 64

__constant__ float NF4_TAB[16] = {
    -1.0f, -0.6961928009986877f, -0.5250730514526367f, -0.39491748809814453f,
    -0.28444138169288635f, -0.18477343022823334f, -0.09105003625154495f, 0.0f,
    0.07958029955625534f, 0.16093020141124725f, 0.24611230194568634f,
    0.33791524171829224f, 0.44070982933044434f, 0.5626170039176941f,
    0.7229568362236023f, 1.0f};

// round(NF4*127): max abs rounding error 0.5/127 in NF4 units
__constant__ int NF4_I8[16] = {
    -127, -88, -67, -50, -36, -23, -12, 0,
    10, 20, 31, 43, 56, 71, 92, 127};

static __device__ __forceinline__ void async_load16(const void* g, void* l) {
  __builtin_amdgcn_global_load_lds(
      (const __attribute__((address_space(1))) void*)g,
      (__attribute__((address_space(3))) void*)l, 16, 0, 0);
}
static __device__ __forceinline__ void async_load4(const void* g, void* l) {
  __builtin_amdgcn_global_load_lds(
      (const __attribute__((address_space(1))) void*)g,
      (__attribute__((address_space(3))) void*)l, 4, 0, 0);
}

// ---------------------------------------------------------------------------
// W -> i8: 4 packed int32 (one code-pair each) -> 8 i8 (one 8B store).
// wi8 = round(NF4*127); absmax NOT applied here (exact per-block factoring:
// w = wa * NF4 ~= wa * wi8/127, wa consumed as the per-tile MFMA rescale).
// ---------------------------------------------------------------------------
__global__ __launch_bounds__(256) void quant_w_kernel(
    const int* __restrict__ wp, s8* __restrict__ wout) {
  int t = blockIdx.x * 256 + threadIdx.x;   // 7,340,032 threads
  const i32x4 p = __builtin_nontemporal_load(
      reinterpret_cast<const i32x4*>(wp) + t);
  int v[4] = {p.x, p.y, p.z, p.w};
  union { s8 c[8]; int2 v2; } o;
#pragma unroll
  for (int j = 0; j < 4; ++j) {
    o.c[2 * j]     = (s8)NF4_I8[(v[j] >> 4) & 15];
    o.c[2 * j + 1] = (s8)NF4_I8[v[j] & 15];
  }
  reinterpret_cast<int2*>(wout)[t] = o.v2;
}

// ---------------------------------------------------------------------------
// X -> i8 with per-row scale: one block per row (4096 els, 16/thread).
// sxr[row] = rowmax / (127*127)  (both /127 factors folded here).
// ---------------------------------------------------------------------------
__global__ __launch_bounds__(256) void quant_x_kernel(
    const float* __restrict__ x, s8* __restrict__ xi8,
    float* __restrict__ sxr) {
  const int row = blockIdx.x;
  const int tid = threadIdx.x, lane = tid & 63, wid = tid >> 6;
  const float4* xr = reinterpret_cast<const float4*>(x + (size_t)row * 4096);
  float4 v[4];
  float mx = 0.0f;
#pragma unroll
  for (int i = 0; i < 4; ++i) {
    v[i] = xr[tid * 4 + i];
    mx = fmaxf(mx, fmaxf(fmaxf(fabsf(v[i].x), fabsf(v[i].y)),
                         fmaxf(fabsf(v[i].z), fabsf(v[i].w))));
  }
#pragma unroll
  for (int off = 32; off; off >>= 1)
    mx = fmaxf(mx, __shfl_xor(mx, off));
  __shared__ float red[4];
  if (lane == 0) red[wid] = mx;
  __syncthreads();
  mx = fmaxf(fmaxf(red[0], red[1]), fmaxf(red[2], red[3]));
  float rs = mx > 0.0f ? 127.0f / mx : 0.0f;
  union { s8 c[16]; i32x4 q; } o;
#pragma unroll
  for (int i = 0; i < 4; ++i) {
    o.c[4 * i + 0] = (s8)(int)rintf(v[i].x * rs);
    o.c[4 * i + 1] = (s8)(int)rintf(v[i].y * rs);
    o.c[4 * i + 2] = (s8)(int)rintf(v[i].z * rs);
    o.c[4 * i + 3] = (s8)(int)rintf(v[i].w * rs);
  }
  reinterpret_cast<i32x4*>(xi8 + (size_t)row * 4096)[tid] = o.q;
  if (tid == 0) sxr[row] = mx / 16129.0f;
}

// ---------------------------------------------------------------------------
// Transpose wa [N][64] -> swT [64][N] so per-K-tile sw is contiguous.
// ---------------------------------------------------------------------------
__global__ __launch_bounds__(256) void swt_kernel(
    const float* __restrict__ wa, float* __restrict__ swT) {
  int i = blockIdx.x * 256 + threadIdx.x;   // 917,504 threads exactly
  int kb = i / N_OUT, n = i - kb * N_OUT;
  swT[i] = wa[(size_t)n * 64 + kb];
}

// ---------------------------------------------------------------------------
// 256x256x64 depth-2 pipelined INT8 GEMM, mfma_i32_16x16x64_i8, one barrier
// per K-tile (R7 skeleton). Per K-tile: dot_i32 over K=64 is exact; rescale
// acc[m][n] += sw[n] * (float)dot (sw = raw wa[n][kb], staged 1KB/tile);
// per-row x-scale applied once in the epilogue. LDS: 2x(A 16K + B 16K) +
// 2x1KB sw = 66KB. Swizzle: 16B chunk c' = c ^ (row&3) (rows are 64B of i8;
// wave-read pattern gives uniform 2-way bank aliasing = free per m136).
// Race safety: stages write buf[P^1] only; VM(0)+barrier per tile; memory
// ops pinned between consecutive VM asms.
// ---------------------------------------------------------------------------
__global__ __launch_bounds__(512, 2) void gemm_nf4_i8(
    const s8* __restrict__ A,    // [M][K] i8
    const s8* __restrict__ B,    // [N][K] i8
    float* __restrict__ C, const int* __restrict__ bp,
    const float* __restrict__ ba, const float* __restrict__ swT,
    const float* __restrict__ sxr) {
  constexpr int K = K_IN, N = N_OUT;
  extern __shared__ char smem[];
  char* sA = smem;                          // [2][256][64] i8
  char* sB = smem + 32768;                  // [2][256][64] i8
  float* sSw = (float*)(smem + 65536);      // [2][256] f32

  const int tid = threadIdx.x;
  const int w = tid >> 6, lane = tid & 63;
  const int r = lane & 15, kq = lane >> 4;
  const int wr = w >> 2, wc = w & 3;        // 2 x 4 wave grid

  // bijective XCD swizzle + mt-inner-8 supertile (unchanged from R3)
  int bid = blockIdx.x;
  int cpx = gridDim.x >> 3;
  int wg = (bid & 7) * cpx + (bid >> 3);
  int grp = wg / 448;
  int rem = wg - grp * 448;
  int nt = rem >> 3;
  int mt = grp * 8 + (rem & 7);
  const size_t m0 = (size_t)mt * 256, n0 = (size_t)nt * 256;

  const s8* gA = A + m0 * K;
  const s8* gB = B + n0 * K;

  // read-side swizzled chunk offset (bytes); row&3 == r&3 for all frag rows
  const int cswz = ((kq ^ (r & 3)) << 4);
  // stage-side: lane covers row (base + lane>>2), chunk (lane&3)^((lane>>2)&3)
  const int cg16 = (((lane & 3) ^ ((lane >> 2) & 3)) << 4);
  const int rl = lane >> 2;

  // hoisted stage source pointers (advance by s*64 bytes per K-tile)
  const s8* stA0 = gA + (size_t)(w * 16 + rl) * K + cg16;
  const s8* stA1 = gA + (size_t)(128 + w * 16 + rl) * K + cg16;
  const s8* stB0 = gB + (size_t)(w * 16 + rl) * K + cg16;
  const s8* stB1 = gB + (size_t)(128 + w * 16 + rl) * K + cg16;
  const float* swp = swT + n0;              // + s*N + w*64 + lane per tile

  f32x4 acc[8][4] = {};
  i32x4 aF[4], bF[4];
  float swv[4];
  const i32x4 izero = {0, 0, 0, 0};

#define BAR() __builtin_amdgcn_s_barrier()
#define VM(n) asm volatile("s_waitcnt vmcnt(" #n ")" ::: "memory")

#define STAGE_AB(P, s) do {                                                  \
    async_load16(stA0 + (size_t)(s) * 64, sA + (P) * 16384 + w * 1024);      \
    async_load16(stA1 + (size_t)(s) * 64, sA + (P) * 16384 + 8192 + w * 1024);\
    async_load16(stB0 + (size_t)(s) * 64, sB + (P) * 16384 + w * 1024);      \
    async_load16(stB1 + (size_t)(s) * 64, sB + (P) * 16384 + 8192 + w * 1024);\
    if (w < 4)                                                               \
      async_load4(swp + (size_t)(s) * N + w * 64 + lane,                     \
                  (char*)(sSw + (P) * 256 + w * 64));                        \
  } while (0)

#define READ_A(P, mq) do {                                                   \
    const char* pa_ = sA + (P) * 16384 + (wr * 128 + (mq) * 64 + r) * 64;    \
    _Pragma("unroll")                                                        \
    for (int m_ = 0; m_ < 4; ++m_)                                           \
      aF[m_] = *(const i32x4*)(pa_ + m_ * 1024 + cswz);                      \
  } while (0)

#define READ_B(P, nq) do {                                                   \
    const char* pb_ = sB + (P) * 16384 + (wc * 64 + (nq) * 32 + r) * 64;     \
    _Pragma("unroll")                                                        \
    for (int n_ = 0; n_ < 2; ++n_) {                                         \
      bF[(nq) * 2 + n_] = *(const i32x4*)(pb_ + n_ * 1024 + cswz);           \
      swv[(nq) * 2 + n_] = sSw[(P) * 256 + wc * 64 + (nq) * 32 + n_ * 16 + r];\
    }                                                                        \
  } while (0)

#define MFMA_Q(mq, nq) do {                                                  \
    __builtin_amdgcn_s_setprio(1);                                           \
    _Pragma("unroll")                                                        \
    for (int m_ = 0; m_ < 4; ++m_)                                           \
      _Pragma("unroll")                                                      \
      for (int n_ = 0; n_ < 2; ++n_) {                                       \
        i32x4 ip_ = __builtin_amdgcn_mfma_i32_16x16x64_i8(                   \
            aF[m_], bF[(nq) * 2 + n_], izero, 0, 0, 0);                      \
        _Pragma("unroll")                                                    \
        for (int j_ = 0; j_ < 4; ++j_)                                       \
          acc[(mq) * 4 + m_][(nq) * 2 + n_][j_] +=                           \
              (float)ip_[j_] * swv[(nq) * 2 + n_];                           \
      }                                                                      \
    __builtin_amdgcn_s_setprio(0);                                           \
  } while (0)

  // BODY(tile s, buffer P): barrier-free interior; stage next tile early.
#define BODY(s, P, DO_STAGE, DO_VMBAR) do {                                  \
    READ_A(P, 0); READ_B(P, 0);                                              \
    if (DO_STAGE) STAGE_AB((P) ^ 1, (s) + 1);                                \
    MFMA_Q(0, 0);                                                            \
    READ_B(P, 1); MFMA_Q(0, 1);                                              \
    READ_A(P, 1); MFMA_Q(1, 0); MFMA_Q(1, 1);                                \
    if (DO_VMBAR) { VM(0); BAR(); }                                          \
  } while (0)

  // prologue: stage tile 0 into buf[0]
  STAGE_AB(0, 0);
  VM(0); BAR();

  for (int s = 0; s < NTILE - 2; s += 2) {
    BODY(s, 0, 1, 1);
    BODY(s + 1, 1, 1, 1);
  }
  BODY(NTILE - 2, 0, 1, 1);   // stages tile 63 into buf[1]
  BODY(NTILE - 1, 1, 0, 0);   // tail: no stage, no sync

  // epilogue: per-row x-scale + NF4 bias; plain stores (R10)
  // C/D layout (16x16): col = lane&15, row = kq*4 + j
  float bias[4];
#pragma unroll
  for (int ni = 0; ni < 4; ++ni) {
    int col = (int)n0 + wc * 64 + ni * 16 + r;
    int byte = bp[col >> 1];
    int code = (col & 1) ? (byte & 15) : ((byte >> 4) & 15);
    bias[ni] = NF4_TAB[code] * ba[col >> 6];
  }
#pragma unroll
  for (int mi = 0; mi < 8; ++mi) {
    size_t row0 = m0 + wr * 128 + mi * 16 + kq * 4;
    const f32x4 sxv = *reinterpret_cast<const f32x4*>(sxr + row0);
#pragma unroll
    for (int ni = 0; ni < 4; ++ni) {
      size_t col = n0 + wc * 64 + ni * 16 + r;
#pragma unroll
      for (int j = 0; j < 4; ++j)
        C[(row0 + j) * N + col] = acc[mi][ni][j] * sxv[j] + bias[ni];
    }
  }
#undef BODY
#undef MFMA_Q
#undef READ_B
#undef READ_A
#undef STAGE_AB
#undef VM
#undef BAR
}

extern "C" void kernel_launch(void* const* d_in, const int* in_sizes, int n_in,
                              void* d_out, int out_size, void* d_ws,
                              size_t ws_size, hipStream_t stream) {
  const float* x  = (const float*)d_in[0];
  const int* wp   = (const int*)d_in[1];
  const float* wa = (const float*)d_in[2];
  const int* bp   = (const int*)d_in[3];
  const float* ba = (const float*)d_in[4];
  float* out = (float*)d_out;

  // workspace layout
  s8* Wi8 = (s8*)d_ws;                                   //  58,720,256 B
  s8* Xi8 = Wi8 + (size_t)N_OUT * K_IN;                  //  33,554,432 B
  float* swT = (float*)(Xi8 + (size_t)M_ROWS * K_IN);    //   3,670,016 B
  float* sxr = swT + (size_t)64 * N_OUT;                 //      32,768 B

  quant_w_kernel<<<28672, 256, 0, stream>>>(wp, Wi8);
  quant_x_kernel<<<8192, 256, 0, stream>>>(x, Xi8, sxr);
  swt_kernel<<<3584, 256, 0, stream>>>(wa, swT);

  hipFuncSetAttribute(reinterpret_cast<const void*>(gemm_nf4_i8),
                      hipFuncAttributeMaxDynamicSharedMemorySize, 67584);
  // 32 m-tiles x 56 n-tiles
  gemm_nf4_i8<<<1792, 512, 67584, stream>>>(Xi8, Wi8, out, bp, ba, swT, sxr);
}

// Round 14
// 619.702 us; speedup vs baseline: 5.9657x; 5.9657x over previous
//
#include <hip/hip_runtime.h>

typedef unsigned short u16;
typedef signed char s8;
typedef __attribute__((ext_vector_type(4))) float f32x4;
typedef __attribute__((ext_vector_type(4))) int i32x4;

#define M_ROWS 8192
#define N_OUT  14336
#define K_IN   4096
#define NTILE  64   // K_IN / 64

__constant__ float NF4_TAB[16] = {
    -1.0f, -0.6961928009986877f, -0.5250730514526367f, -0.39491748809814453f,
    -0.28444138169288635f, -0.18477343022823334f, -0.09105003625154495f, 0.0f,
    0.07958029955625534f, 0.16093020141124725f, 0.24611230194568634f,
    0.33791524171829224f, 0.44070982933044434f, 0.5626170039176941f,
    0.7229568362236023f, 1.0f};

static __device__ __forceinline__ void async_load16(const void* g, void* l) {
  __builtin_amdgcn_global_load_lds(
      (const __attribute__((address_space(1))) void*)g,
      (__attribute__((address_space(3))) void*)l, 16, 0, 0);
}

// ---------------------------------------------------------------------------
// W -> i8 with PER-COLUMN scale: one block per output column n.
// Column n = 4096 weights = 2048 packed int32 (each int32 holds one byte =
// two 4-bit codes, hi then lo). Thread t handles 16 weights (8 int32);
// block index = t>>2 (64 weights/block = 4 threads).
// colmax = max_k |wa_blk * NF4[code]|; sn[n] = colmax/127;
// wi8 = round(wa*NF4 * 127/colmax)  -> full-K integer dot is exact.
// ---------------------------------------------------------------------------
__global__ __launch_bounds__(256) void quant_w_kernel(
    const int* __restrict__ wp, const float* __restrict__ wa,
    s8* __restrict__ wout, float* __restrict__ sn) {
  const int n = blockIdx.x;
  const int t = threadIdx.x, lane = t & 63, wid = t >> 6;
  const i32x4 p0 = __builtin_nontemporal_load(
      reinterpret_cast<const i32x4*>(wp) + (size_t)n * 512 + 2 * t);
  const i32x4 p1 = __builtin_nontemporal_load(
      reinterpret_cast<const i32x4*>(wp) + (size_t)n * 512 + 2 * t + 1);
  const float am = wa[n * 64 + (t >> 2)];

  float v[16];
  int pv[8] = {p0.x, p0.y, p0.z, p0.w, p1.x, p1.y, p1.z, p1.w};
  float mx = 0.0f;
#pragma unroll
  for (int i = 0; i < 8; ++i) {
    v[2 * i]     = NF4_TAB[(pv[i] >> 4) & 15];
    v[2 * i + 1] = NF4_TAB[pv[i] & 15];
  }
#pragma unroll
  for (int i = 0; i < 16; ++i) mx = fmaxf(mx, fabsf(v[i]));
  mx *= am;                         // candidate colmax from this thread
#pragma unroll
  for (int off = 32; off; off >>= 1) mx = fmaxf(mx, __shfl_xor(mx, off));
  __shared__ float red[4];
  if (lane == 0) red[wid] = mx;
  __syncthreads();
  const float colmax = fmaxf(fmaxf(red[0], red[1]), fmaxf(red[2], red[3]));
  const float inv = colmax > 0.0f ? (127.0f * am) / colmax : 0.0f;

  union { s8 c[16]; i32x4 q; } o;
#pragma unroll
  for (int i = 0; i < 16; ++i) o.c[i] = (s8)(int)rintf(v[i] * inv);
  reinterpret_cast<i32x4*>(wout)[(size_t)n * 256 + t] = o.q;
  if (t == 0) sn[n] = colmax * (1.0f / 127.0f);
}

// ---------------------------------------------------------------------------
// X -> i8 with per-row scale (proven in R13): one block per row.
// sxr[row] = rowmax/127.
// ---------------------------------------------------------------------------
__global__ __launch_bounds__(256) void quant_x_kernel(
    const float* __restrict__ x, s8* __restrict__ xi8,
    float* __restrict__ sxr) {
  const int row = blockIdx.x;
  const int tid = threadIdx.x, lane = tid & 63, wid = tid >> 6;
  const float4* xr = reinterpret_cast<const float4*>(x + (size_t)row * 4096);
  float4 v[4];
  float mx = 0.0f;
#pragma unroll
  for (int i = 0; i < 4; ++i) {
    v[i] = xr[tid * 4 + i];
    mx = fmaxf(mx, fmaxf(fmaxf(fabsf(v[i].x), fabsf(v[i].y)),
                         fmaxf(fabsf(v[i].z), fabsf(v[i].w))));
  }
#pragma unroll
  for (int off = 32; off; off >>= 1) mx = fmaxf(mx, __shfl_xor(mx, off));
  __shared__ float red[4];
  if (lane == 0) red[wid] = mx;
  __syncthreads();
  mx = fmaxf(fmaxf(red[0], red[1]), fmaxf(red[2], red[3]));
  float rs = mx > 0.0f ? 127.0f / mx : 0.0f;
  union { s8 c[16]; i32x4 q; } o;
#pragma unroll
  for (int i = 0; i < 4; ++i) {
    o.c[4 * i + 0] = (s8)(int)rintf(v[i].x * rs);
    o.c[4 * i + 1] = (s8)(int)rintf(v[i].y * rs);
    o.c[4 * i + 2] = (s8)(int)rintf(v[i].z * rs);
    o.c[4 * i + 3] = (s8)(int)rintf(v[i].w * rs);
  }
  reinterpret_cast<i32x4*>(xi8 + (size_t)row * 4096)[tid] = o.q;
  if (tid == 0) sxr[row] = mx * (1.0f / 127.0f);
}

// ---------------------------------------------------------------------------
// 256x256x64 depth-2 pipelined PURE-INT8 GEMM, mfma_i32_16x16x64_i8, one
// barrier per K-tile (R7 skeleton). Full-K i32 accumulation THROUGH the MFMA
// C operand (exact: |dot| <= 4096*127^2 = 6.6e7 < 2^31) -> acc lives in
// AGPRs, zero VALU in the loop (R13's spill cause eliminated). Scales
// sn[col]*sxr[row] applied once in the epilogue.
// LDS: 2 x (A 16K + B 16K) = 64 KB. Swizzle for 64B rows:
//   LDS[row][slot] holds global chunk slot ^ ((row>>1)&3);
//   read slot = kq ^ ((r>>1)&3) -> bank granule (4r+slot) mod 8 is a full
//   permutation over r=0..7 (enumerated: 0,4,1,5,2,6,3,7) -> 2-way = free
//   (fixes R13's 4-way from the r&3 XOR).
// Race safety identical to R7.
// ---------------------------------------------------------------------------
__global__ __launch_bounds__(512, 2) void gemm_nf4_i8(
    const s8* __restrict__ A,    // [M][K] i8
    const s8* __restrict__ B,    // [N][K] i8
    float* __restrict__ C, const int* __restrict__ bp,
    const float* __restrict__ ba, const float* __restrict__ sn,
    const float* __restrict__ sxr) {
  constexpr int K = K_IN, N = N_OUT;
  extern __shared__ char smem[];
  char* sA = smem;                          // [2][256][64] i8
  char* sB = smem + 32768;                  // [2][256][64] i8

  const int tid = threadIdx.x;
  const int w = tid >> 6, lane = tid & 63;
  const int r = lane & 15, kq = lane >> 4;
  const int wr = w >> 2, wc = w & 3;        // 2 x 4 wave grid

  // bijective XCD swizzle + mt-inner-8 supertile (unchanged)
  int bid = blockIdx.x;
  int cpx = gridDim.x >> 3;
  int wg = (bid & 7) * cpx + (bid >> 3);
  int grp = wg / 448;
  int rem = wg - grp * 448;
  int nt = rem >> 3;
  int mt = grp * 8 + (rem & 7);
  const size_t m0 = (size_t)mt * 256, n0 = (size_t)nt * 256;

  const s8* gA = A + m0 * K;
  const s8* gB = B + n0 * K;

  // read-side swizzled chunk offset (bytes); (row>>1)&3 == (r>>1)&3 since
  // all fragment row bases are multiples of 16
  const int cswz = ((kq ^ ((r >> 1) & 3)) << 4);
  // stage-side: lane l writes slot (l&3) of row base+(l>>2); global chunk
  // g = (l&3) ^ ((row>>1)&3) = (l&3) ^ ((l>>3)&3)  (stage bases mult. of 16)
  const int cg16 = (((lane & 3) ^ ((lane >> 3) & 3)) << 4);
  const int rl = lane >> 2;

  // hoisted stage source pointers (advance by s*64 bytes per K-tile)
  const s8* stA0 = gA + (size_t)(w * 16 + rl) * K + cg16;
  const s8* stA1 = gA + (size_t)(128 + w * 16 + rl) * K + cg16;
  const s8* stB0 = gB + (size_t)(w * 16 + rl) * K + cg16;
  const s8* stB1 = gB + (size_t)(128 + w * 16 + rl) * K + cg16;

  i32x4 acc[8][4] = {};        // integer accumulators -> AGPRs
  i32x4 aF[4], bF[4];

#define BAR() __builtin_amdgcn_s_barrier()
#define VM(n) asm volatile("s_waitcnt vmcnt(" #n ")" ::: "memory")

#define STAGE_AB(P, s) do {                                                   \
    async_load16(stA0 + (size_t)(s) * 64, sA + (P) * 16384 + w * 1024);       \
    async_load16(stA1 + (size_t)(s) * 64, sA + (P) * 16384 + 8192 + w * 1024);\
    async_load16(stB0 + (size_t)(s) * 64, sB + (P) * 16384 + w * 1024);       \
    async_load16(stB1 + (size_t)(s) * 64, sB + (P) * 16384 + 8192 + w * 1024);\
  } while (0)

#define READ_A(P, mq) do {                                                   \
    const char* pa_ = sA + (P) * 16384 + (wr * 128 + (mq) * 64 + r) * 64;    \
    _Pragma("unroll")                                                        \
    for (int m_ = 0; m_ < 4; ++m_)                                           \
      aF[m_] = *(const i32x4*)(pa_ + m_ * 1024 + cswz);                      \
  } while (0)

#define READ_B(P, nq) do {                                                   \
    const char* pb_ = sB + (P) * 16384 + (wc * 64 + (nq) * 32 + r) * 64;     \
    _Pragma("unroll")                                                        \
    for (int n_ = 0; n_ < 2; ++n_)                                           \
      bF[(nq) * 2 + n_] = *(const i32x4*)(pb_ + n_ * 1024 + cswz);           \
  } while (0)

#define MFMA_Q(mq, nq) do {                                                  \
    __builtin_amdgcn_s_setprio(1);                                           \
    _Pragma("unroll")                                                        \
    for (int m_ = 0; m_ < 4; ++m_)                                           \
      _Pragma("unroll")                                                      \
      for (int n_ = 0; n_ < 2; ++n_)                                         \
        acc[(mq) * 4 + m_][(nq) * 2 + n_] =                                  \
            __builtin_amdgcn_mfma_i32_16x16x64_i8(                           \
                aF[m_], bF[(nq) * 2 + n_],                                   \
                acc[(mq) * 4 + m_][(nq) * 2 + n_], 0, 0, 0);                 \
    __builtin_amdgcn_s_setprio(0);                                           \
  } while (0)

  // BODY(tile s, buffer P): barrier-free interior; stage next tile early.
#define BODY(s, P, DO_STAGE, DO_VMBAR) do {                                  \
    READ_A(P, 0); READ_B(P, 0);                                              \
    if (DO_STAGE) STAGE_AB((P) ^ 1, (s) + 1);                                \
    MFMA_Q(0, 0);                                                            \
    READ_B(P, 1); MFMA_Q(0, 1);                                              \
    READ_A(P, 1); MFMA_Q(1, 0); MFMA_Q(1, 1);                                \
    if (DO_VMBAR) { VM(0); BAR(); }                                          \
  } while (0)

  // prologue: stage tile 0 into buf[0]
  STAGE_AB(0, 0);
  VM(0); BAR();

  for (int s = 0; s < NTILE - 2; s += 2) {
    BODY(s, 0, 1, 1);
    BODY(s + 1, 1, 1, 1);
  }
  BODY(NTILE - 2, 0, 1, 1);   // stages tile 63 into buf[1]
  BODY(NTILE - 1, 1, 0, 0);   // tail: no stage, no sync

  // epilogue: out = (float)acc * sn[col] * sxr[row] + bias[col]
  // C/D layout (16x16): col = lane&15, row = kq*4 + j
  float bias[4], snv[4];
#pragma unroll
  for (int ni = 0; ni < 4; ++ni) {
    int col = (int)n0 + wc * 64 + ni * 16 + r;
    int byte = bp[col >> 1];
    int code = (col & 1) ? (byte & 15) : ((byte >> 4) & 15);
    bias[ni] = NF4_TAB[code] * ba[col >> 6];
    snv[ni] = sn[col];
  }
#pragma unroll
  for (int mi = 0; mi < 8; ++mi) {
    size_t row0 = m0 + wr * 128 + mi * 16 + kq * 4;
    const f32x4 sxv = *reinterpret_cast<const f32x4*>(sxr + row0);
#pragma unroll
    for (int ni = 0; ni < 4; ++ni) {
      size_t col = n0 + wc * 64 + ni * 16 + r;
#pragma unroll
      for (int j = 0; j < 4; ++j)
        C[(row0 + j) * N + col] =
            (float)acc[mi][ni][j] * (snv[ni] * sxv[j]) + bias[ni];
    }
  }
#undef BODY
#undef MFMA_Q
#undef READ_B
#undef READ_A
#undef STAGE_AB
#undef VM
#undef BAR
}

extern "C" void kernel_launch(void* const* d_in, const int* in_sizes, int n_in,
                              void* d_out, int out_size, void* d_ws,
                              size_t ws_size, hipStream_t stream) {
  const float* x  = (const float*)d_in[0];
  const int* wp   = (const int*)d_in[1];
  const float* wa = (const float*)d_in[2];
  const int* bp   = (const int*)d_in[3];
  const float* ba = (const float*)d_in[4];
  float* out = (float*)d_out;

  // workspace layout
  s8* Wi8 = (s8*)d_ws;                                   //  58,720,256 B
  s8* Xi8 = Wi8 + (size_t)N_OUT * K_IN;                  //  33,554,432 B
  float* sn  = (float*)(Xi8 + (size_t)M_ROWS * K_IN);    //      57,344 B
  float* sxr = sn + N_OUT;                               //      32,768 B

  quant_w_kernel<<<N_OUT, 256, 0, stream>>>(wp, wa, Wi8, sn);
  quant_x_kernel<<<M_ROWS, 256, 0, stream>>>(x, Xi8, sxr);

  hipFuncSetAttribute(reinterpret_cast<const void*>(gemm_nf4_i8),
                      hipFuncAttributeMaxDynamicSharedMemorySize, 65536);
  // 32 m-tiles x 56 n-tiles
  gemm_nf4_i8<<<1792, 512, 65536, stream>>>(Xi8, Wi8, out, bp, ba, sn, sxr);
}

// Round 15
// 615.514 us; speedup vs baseline: 6.0063x; 1.0068x over previous
//
#include <hip/hip_runtime.h>

typedef unsigned short u16;
typedef signed char s8;
typedef __attribute__((ext_vector_type(4))) float f32x4;
typedef __attribute__((ext_vector_type(4))) int i32x4;

#define M_ROWS 8192
#define N_OUT  14336
#define K_IN   4096
#define NTILE  64   // K_IN / 64

__constant__ float NF4_TAB[16] = {
    -1.0f, -0.6961928009986877f, -0.5250730514526367f, -0.39491748809814453f,
    -0.28444138169288635f, -0.18477343022823334f, -0.09105003625154495f, 0.0f,
    0.07958029955625534f, 0.16093020141124725f, 0.24611230194568634f,
    0.33791524171829224f, 0.44070982933044434f, 0.5626170039176941f,
    0.7229568362236023f, 1.0f};

static __device__ __forceinline__ void async_load16(const void* g, void* l) {
  __builtin_amdgcn_global_load_lds(
      (const __attribute__((address_space(1))) void*)g,
      (__attribute__((address_space(3))) void*)l, 16, 0, 0);
}

// ---------------------------------------------------------------------------
// W -> i8 with PER-COLUMN scale (verified R14): one block per output column.
// ---------------------------------------------------------------------------
__global__ __launch_bounds__(256) void quant_w_kernel(
    const int* __restrict__ wp, const float* __restrict__ wa,
    s8* __restrict__ wout, float* __restrict__ sn) {
  const int n = blockIdx.x;
  const int t = threadIdx.x, lane = t & 63, wid = t >> 6;
  const i32x4 p0 = __builtin_nontemporal_load(
      reinterpret_cast<const i32x4*>(wp) + (size_t)n * 512 + 2 * t);
  const i32x4 p1 = __builtin_nontemporal_load(
      reinterpret_cast<const i32x4*>(wp) + (size_t)n * 512 + 2 * t + 1);
  const float am = wa[n * 64 + (t >> 2)];

  float v[16];
  int pv[8] = {p0.x, p0.y, p0.z, p0.w, p1.x, p1.y, p1.z, p1.w};
  float mx = 0.0f;
#pragma unroll
  for (int i = 0; i < 8; ++i) {
    v[2 * i]     = NF4_TAB[(pv[i] >> 4) & 15];
    v[2 * i + 1] = NF4_TAB[pv[i] & 15];
  }
#pragma unroll
  for (int i = 0; i < 16; ++i) mx = fmaxf(mx, fabsf(v[i]));
  mx *= am;
#pragma unroll
  for (int off = 32; off; off >>= 1) mx = fmaxf(mx, __shfl_xor(mx, off));
  __shared__ float red[4];
  if (lane == 0) red[wid] = mx;
  __syncthreads();
  const float colmax = fmaxf(fmaxf(red[0], red[1]), fmaxf(red[2], red[3]));
  const float inv = colmax > 0.0f ? (127.0f * am) / colmax : 0.0f;

  union { s8 c[16]; i32x4 q; } o;
#pragma unroll
  for (int i = 0; i < 16; ++i) o.c[i] = (s8)(int)rintf(v[i] * inv);
  reinterpret_cast<i32x4*>(wout)[(size_t)n * 256 + t] = o.q;
  if (t == 0) sn[n] = colmax * (1.0f / 127.0f);
}

// ---------------------------------------------------------------------------
// X -> i8 with per-row scale (verified R13/R14): one block per row.
// ---------------------------------------------------------------------------
__global__ __launch_bounds__(256) void quant_x_kernel(
    const float* __restrict__ x, s8* __restrict__ xi8,
    float* __restrict__ sxr) {
  const int row = blockIdx.x;
  const int tid = threadIdx.x, lane = tid & 63, wid = tid >> 6;
  const float4* xr = reinterpret_cast<const float4*>(x + (size_t)row * 4096);
  float4 v[4];
  float mx = 0.0f;
#pragma unroll
  for (int i = 0; i < 4; ++i) {
    v[i] = xr[tid * 4 + i];
    mx = fmaxf(mx, fmaxf(fmaxf(fabsf(v[i].x), fabsf(v[i].y)),
                         fmaxf(fabsf(v[i].z), fabsf(v[i].w))));
  }
#pragma unroll
  for (int off = 32; off; off >>= 1) mx = fmaxf(mx, __shfl_xor(mx, off));
  __shared__ float red[4];
  if (lane == 0) red[wid] = mx;
  __syncthreads();
  mx = fmaxf(fmaxf(red[0], red[1]), fmaxf(red[2], red[3]));
  float rs = mx > 0.0f ? 127.0f / mx : 0.0f;
  union { s8 c[16]; i32x4 q; } o;
#pragma unroll
  for (int i = 0; i < 4; ++i) {
    o.c[4 * i + 0] = (s8)(int)rintf(v[i].x * rs);
    o.c[4 * i + 1] = (s8)(int)rintf(v[i].y * rs);
    o.c[4 * i + 2] = (s8)(int)rintf(v[i].z * rs);
    o.c[4 * i + 3] = (s8)(int)rintf(v[i].w * rs);
  }
  reinterpret_cast<i32x4*>(xi8 + (size_t)row * 4096)[tid] = o.q;
  if (tid == 0) sxr[row] = mx * (1.0f / 127.0f);
}

// ---------------------------------------------------------------------------
// 256x128 INT8 GEMM, mfma_i32_16x16x64_i8, depth-2, single-phase body,
// __launch_bounds__(512,4) -> 2 BLOCKS PER CU (the overlap mechanism: two
// independent blocks at uncorrelated loop phases overlap one block's LDS-read
// window and vmcnt drain with the other's MFMA window; m114 cross-wave pipe
// overlap). Per wave: 64x64 output = acc[4][4] i32x4 (64 regs, AGPR via MFMA
// C chain); aF[4] + streamed bF (4) keep VGPRs ~50 -> fits the 128-reg cap.
// LDS 48KB/block (2 bufs x (A 256x64 + B 128x64) i8); x2 blocks = 96KB.
// Swizzle identical to R14 (verified 0-conflict): read slot kq^((r>>1)&3),
// stage chunk (lane&3)^((lane>>3)&3); all row bases multiples of 16.
// Pure-i32 accumulation (exact), scales applied in epilogue (R14, abs 1.30).
// ---------------------------------------------------------------------------
__global__ __launch_bounds__(512, 4) void gemm_nf4_i8(
    const s8* __restrict__ A,    // [M][K] i8
    const s8* __restrict__ B,    // [N][K] i8
    float* __restrict__ C, const int* __restrict__ bp,
    const float* __restrict__ ba, const float* __restrict__ sn,
    const float* __restrict__ sxr) {
  constexpr int K = K_IN, N = N_OUT;
  extern __shared__ char smem[];
  char* sA = smem;                          // [2][256][64] i8 = 32 KB
  char* sB = smem + 32768;                  // [2][128][64] i8 = 16 KB

  const int tid = threadIdx.x;
  const int w = tid >> 6, lane = tid & 63;
  const int r = lane & 15, kq = lane >> 4;
  const int wr = w >> 1, wc = w & 1;        // 4 x 2 wave grid, 64x64 each

  // bijective XCD swizzle (3584 % 8 == 0) + mt-inner-8 supertile
  int bid = blockIdx.x;
  int cpx = gridDim.x >> 3;                 // 448
  int wg = (bid & 7) * cpx + (bid >> 3);
  int grp = wg / 896;                       // 896 = 112 nt * 8 mt
  int rem = wg - grp * 896;
  int nt = rem >> 3;                        // 0..111
  int mt = grp * 8 + (rem & 7);             // 0..31
  const size_t m0 = (size_t)mt * 256, n0 = (size_t)nt * 128;

  const s8* gA = A + m0 * K;
  const s8* gB = B + n0 * K;

  // read-side swizzled chunk offset (bytes); row bases all multiples of 16
  const int cswz = ((kq ^ ((r >> 1) & 3)) << 4);
  // stage-side global chunk (involution partner, R14-verified)
  const int cg16 = (((lane & 3) ^ ((lane >> 3) & 3)) << 4);
  const int rl = lane >> 2;

  // hoisted stage source pointers (advance by s*64 bytes per K-tile)
  const s8* stA0 = gA + (size_t)(w * 16 + rl) * K + cg16;
  const s8* stA1 = gA + (size_t)(128 + w * 16 + rl) * K + cg16;
  const s8* stB0 = gB + (size_t)(w * 16 + rl) * K + cg16;

  i32x4 acc[4][4] = {};        // 64 regs -> AGPRs via MFMA C chain
  i32x4 aF[4];

#define BAR() __builtin_amdgcn_s_barrier()
#define VM(n) asm volatile("s_waitcnt vmcnt(" #n ")" ::: "memory")

#define STAGE_AB(P, s) do {                                                   \
    async_load16(stA0 + (size_t)(s) * 64, sA + (P) * 16384 + w * 1024);       \
    async_load16(stA1 + (size_t)(s) * 64, sA + (P) * 16384 + 8192 + w * 1024);\
    async_load16(stB0 + (size_t)(s) * 64, sB + (P) * 8192 + w * 1024);        \
  } while (0)

#define READ_A(P) do {                                                       \
    const char* pa_ = sA + (P) * 16384 + (wr * 64 + r) * 64;                 \
    _Pragma("unroll")                                                        \
    for (int m_ = 0; m_ < 4; ++m_)                                           \
      aF[m_] = *(const i32x4*)(pa_ + m_ * 1024 + cswz);                      \
  } while (0)

  // stream one B fragment at a time (4 live VGPRs), 4 MFMA per fragment
#define MFMA_ALL(P) do {                                                     \
    const char* pb_ = sB + (P) * 8192 + (wc * 64 + r) * 64;                  \
    __builtin_amdgcn_s_setprio(1);                                           \
    _Pragma("unroll")                                                        \
    for (int n_ = 0; n_ < 4; ++n_) {                                         \
      i32x4 bF_ = *(const i32x4*)(pb_ + n_ * 1024 + cswz);                   \
      _Pragma("unroll")                                                      \
      for (int m_ = 0; m_ < 4; ++m_)                                         \
        acc[m_][n_] = __builtin_amdgcn_mfma_i32_16x16x64_i8(                 \
            aF[m_], bF_, acc[m_][n_], 0, 0, 0);                              \
    }                                                                        \
    __builtin_amdgcn_s_setprio(0);                                           \
  } while (0)

#define BODY(s, P, DO_STAGE, DO_VMBAR) do {                                  \
    READ_A(P);                                                               \
    if (DO_STAGE) STAGE_AB((P) ^ 1, (s) + 1);                                \
    MFMA_ALL(P);                                                             \
    if (DO_VMBAR) { VM(0); BAR(); }                                          \
  } while (0)

  // prologue: stage tile 0 into buf[0]
  STAGE_AB(0, 0);
  VM(0); BAR();

  for (int s = 0; s < NTILE - 2; s += 2) {
    BODY(s, 0, 1, 1);
    BODY(s + 1, 1, 1, 1);
  }
  BODY(NTILE - 2, 0, 1, 1);   // stages tile 63 into buf[1]
  BODY(NTILE - 1, 1, 0, 0);   // tail: no stage, no sync

  // epilogue: out = (float)acc * sn[col] * sxr[row] + bias[col]
  // C/D layout (16x16): col = lane&15, row = kq*4 + j  (R14-verified)
  float bias[4], snv[4];
#pragma unroll
  for (int ni = 0; ni < 4; ++ni) {
    int col = (int)n0 + wc * 64 + ni * 16 + r;
    int byte = bp[col >> 1];
    int code = (col & 1) ? (byte & 15) : ((byte >> 4) & 15);
    bias[ni] = NF4_TAB[code] * ba[col >> 6];
    snv[ni] = sn[col];
  }
#pragma unroll
  for (int mi = 0; mi < 4; ++mi) {
    size_t row0 = m0 + wr * 64 + mi * 16 + kq * 4;
    const f32x4 sxv = *reinterpret_cast<const f32x4*>(sxr + row0);
#pragma unroll
    for (int ni = 0; ni < 4; ++ni) {
      size_t col = n0 + wc * 64 + ni * 16 + r;
#pragma unroll
      for (int j = 0; j < 4; ++j)
        C[(row0 + j) * N + col] =
            (float)acc[mi][ni][j] * (snv[ni] * sxv[j]) + bias[ni];
    }
  }
#undef BODY
#undef MFMA_ALL
#undef READ_A
#undef STAGE_AB
#undef VM
#undef BAR
}

extern "C" void kernel_launch(void* const* d_in, const int* in_sizes, int n_in,
                              void* d_out, int out_size, void* d_ws,
                              size_t ws_size, hipStream_t stream) {
  const float* x  = (const float*)d_in[0];
  const int* wp   = (const int*)d_in[1];
  const float* wa = (const float*)d_in[2];
  const int* bp   = (const int*)d_in[3];
  const float* ba = (const float*)d_in[4];
  float* out = (float*)d_out;

  // workspace layout
  s8* Wi8 = (s8*)d_ws;                                   //  58,720,256 B
  s8* Xi8 = Wi8 + (size_t)N_OUT * K_IN;                  //  33,554,432 B
  float* sn  = (float*)(Xi8 + (size_t)M_ROWS * K_IN);    //      57,344 B
  float* sxr = sn + N_OUT;                               //      32,768 B

  quant_w_kernel<<<N_OUT, 256, 0, stream>>>(wp, wa, Wi8, sn);
  quant_x_kernel<<<M_ROWS, 256, 0, stream>>>(x, Xi8, sxr);

  hipFuncSetAttribute(reinterpret_cast<const void*>(gemm_nf4_i8),
                      hipFuncAttributeMaxDynamicSharedMemorySize, 49152);
  // 32 m-tiles x 112 n-tiles
  gemm_nf4_i8<<<3584, 512, 49152, stream>>>(Xi8, Wi8, out, bp, ba, sn, sxr);
}